// Round 1
// baseline (134.348 us; speedup 1.0000x reference)
//
#include <hip/hip_runtime.h>
#include <math.h>

// Problem constants (from reference)
#define BB   2
#define LQ   24
#define LK   24
#define NH   4
#define DM   32     // d_model
#define DF   32     // d_feat
#define HW   256    // 16x16
#define NEG  0.1f

__device__ __forceinline__ float lrelu(float x) { return x >= 0.f ? x : NEG * x; }

// -----------------------------------------------------------------------------
// K1: one block per (b,n,j) image (192 blocks, 256 threads = one thread/pixel).
//  - project V head slice -> vh (global)
//  - project K head slice -> zero-padded LDS image (32ch x 20x20)
//  - 5x5 conv over LDS -> ck  (b_attn omitted: cancels in softmax)
// -----------------------------------------------------------------------------
__global__ __launch_bounds__(256) void k_proj_conv(
    const float* __restrict__ kin, const float* __restrict__ vin,
    const float* __restrict__ wk, const float* __restrict__ bk,
    const float* __restrict__ wv, const float* __restrict__ bv,
    const float* __restrict__ wat,
    float* __restrict__ vh, float* __restrict__ ck)
{
    const int img = blockIdx.x;            // (b*NH + n)*LK + j
    const int b   = img / (NH * LK);
    const int n   = (img / LK) % NH;
    const int j   = img % LK;
    const int hw  = threadIdx.x;
    const int h   = hw >> 4, w = hw & 15;

    __shared__ float skh[DM][20 * 20];     // zero-padded K-projection image

    // zero the whole padded LDS image (incl. interior), then barrier
    for (int idx = hw; idx < DM * 400; idx += 256) ((float*)skh)[idx] = 0.f;

    const float* kb = kin + (size_t)((b * LK + j) * DF) * HW + hw;
    const float* vb = vin + (size_t)((b * LK + j) * DF) * HW + hw;

    float xr[DF];

    // ---- V projection (no LDS needed) ----
    #pragma unroll
    for (int c = 0; c < DF; c++) xr[c] = vb[c * HW];
    #pragma unroll 4
    for (int d = 0; d < DM; d++) {
        const int o = n * DM + d;
        const float* wr = wv + o * DF;
        float acc = bv[o];
        #pragma unroll
        for (int c = 0; c < DF; c++) acc += xr[c] * wr[c];
        vh[(size_t)img * (DM * HW) + d * HW + hw] = lrelu(acc);
    }

    // ---- K projection into padded LDS ----
    #pragma unroll
    for (int c = 0; c < DF; c++) xr[c] = kb[c * HW];
    __syncthreads();   // zero-fill complete before interior writes
    #pragma unroll 4
    for (int d = 0; d < DM; d++) {
        const int o = n * DM + d;
        const float* wr = wk + o * DF;
        float acc = bk[o];
        #pragma unroll
        for (int c = 0; c < DF; c++) acc += xr[c] * wr[c];
        skh[d][(h + 2) * 20 + (w + 2)] = lrelu(acc);
    }
    __syncthreads();

    // ---- 5x5 conv, padding baked into LDS (no bounds checks) ----
    float acc = 0.f;
    #pragma unroll 2
    for (int c = 0; c < DM; c++) {
        const float* wc = wat + c * 25;
        #pragma unroll
        for (int ky = 0; ky < 5; ky++) {
            const float* row = &skh[c][(h + ky) * 20 + w];
            #pragma unroll
            for (int kx = 0; kx < 5; kx++)
                acc += row[kx] * wc[ky * 5 + kx];
        }
    }
    ck[img * HW + hw] = acc;
}

// -----------------------------------------------------------------------------
// K2: one block per (b,n) x channel-group (64 blocks).
//  - softmax over j (24) per pixel, in registers
//  - write attn output broadcast over i (this block's 3 i's)
//  - res[c] = sum_j A[j] * vh[j,c]  for this block's 4 c's
// -----------------------------------------------------------------------------
__global__ __launch_bounds__(256) void k_softmax_res(
    const float* __restrict__ ck, const float* __restrict__ vh,
    float* __restrict__ res, float* __restrict__ attn_out)
{
    const int bn = blockIdx.x >> 3;   // 0..7  = b*NH+n
    const int cg = blockIdx.x & 7;    // 0..7
    const int hw = threadIdx.x;

    float e[LK];
    const float* cb = ck + bn * LK * HW + hw;
    float m = -1e30f;
    #pragma unroll
    for (int j = 0; j < LK; j++) { e[j] = cb[j * HW]; m = fmaxf(m, e[j]); }
    float s = 0.f;
    #pragma unroll
    for (int j = 0; j < LK; j++) { e[j] = expf(e[j] - m); s += e[j]; }
    const float inv = 1.f / s;
    #pragma unroll
    for (int j = 0; j < LK; j++) e[j] *= inv;

    // attn output: identical for every query i (cq + b_attn cancel in softmax)
    for (int i = cg * 3; i < cg * 3 + 3; i++) {
        float* ao = attn_out + (size_t)((bn * LQ + i) * LK) * HW + hw;
        #pragma unroll
        for (int j = 0; j < LK; j++) ao[j * HW] = e[j];
    }

    // res (independent of i as well)
    for (int c4 = 0; c4 < 4; c4++) {
        const int c = cg * 4 + c4;
        const float* vp = vh + (size_t)bn * LK * DM * HW + c * HW + hw;
        float acc = 0.f;
        #pragma unroll
        for (int j = 0; j < LK; j++) acc += e[j] * vp[j * DM * HW];
        res[(bn * DM + c) * HW + hw] = acc;
    }
}

// -----------------------------------------------------------------------------
// K3: final FC (128 -> 32), broadcast over l = 0..23. One block per (b,o).
// -----------------------------------------------------------------------------
__global__ __launch_bounds__(256) void k_fc(
    const float* __restrict__ res, const float* __restrict__ wfc,
    float* __restrict__ out)
{
    const int b  = blockIdx.x >> 5;
    const int o  = blockIdx.x & 31;
    const int hw = threadIdx.x;

    const float* rp = res + b * (NH * DM) * HW + hw;
    const float* wr = wfc + o * (NH * DM);
    float acc = 0.f;
    #pragma unroll 8
    for (int nc = 0; nc < NH * DM; nc++) acc += wr[nc] * rp[nc * HW];

    #pragma unroll
    for (int l = 0; l < LQ; l++)
        out[(size_t)((b * LQ + l) * DM + o) * HW + hw] = acc;
}

// -----------------------------------------------------------------------------
extern "C" void kernel_launch(void* const* d_in, const int* in_sizes, int n_in,
                              void* d_out, int out_size, void* d_ws, size_t ws_size,
                              hipStream_t stream)
{
    // setup_inputs order: q,k,v,wq,bq,wk,bk,wv,bv,w_attn,b_attn,w_fc
    const float* k_in = (const float*)d_in[1];
    const float* v_in = (const float*)d_in[2];
    const float* wk   = (const float*)d_in[5];
    const float* bk   = (const float*)d_in[6];
    const float* wv   = (const float*)d_in[7];
    const float* bv   = (const float*)d_in[8];
    const float* wat  = (const float*)d_in[9];
    const float* wfc  = (const float*)d_in[11];
    // q, wq, bq, b_attn are provably unused (cancel in softmax over keys).

    float* out  = (float*)d_out;                       // (B,LQ,DM,H,W) = 393216
    float* attn = out + (size_t)BB * LQ * DM * HW;     // (B,NH,LQ,LK,1,H,W)

    float* vh  = (float*)d_ws;                                  // 1,572,864 f
    float* ck  = vh + (size_t)BB * NH * LK * DM * HW;           //    49,152 f
    float* res = ck + (size_t)BB * NH * LK * HW;                //    65,536 f

    hipLaunchKernelGGL(k_proj_conv, dim3(BB * NH * LK), dim3(256), 0, stream,
                       k_in, v_in, wk, bk, wv, bv, wat, vh, ck);
    hipLaunchKernelGGL(k_softmax_res, dim3(BB * NH * 8), dim3(256), 0, stream,
                       ck, vh, res, attn);
    hipLaunchKernelGGL(k_fc, dim3(BB * DM), dim3(256), 0, stream,
                       res, wfc, out);
}

// Round 2
// 102.423 us; speedup vs baseline: 1.3117x; 1.3117x over previous
//
#include <hip/hip_runtime.h>
#include <math.h>

// Problem constants (from reference)
#define BB   2
#define LQ   24
#define LK   24
#define NH   4
#define DM   32     // d_model
#define DF   32     // d_feat
#define HW   256    // 16x16
#define NEG  0.1f

// Padded LDS image: 20 rows, pitch 24 floats. Pitch 24 => the 4 h-rows of a
// wave sit at bank offsets {0,24,16,8} mod 32: exact 2-way aliasing, which is
// free on gfx950 (m136). Pitch 20 gave 3-way (1.28M conflicts in round 1).
#define PITCH 24
#define CHPAD (20 * PITCH)   // 480 floats per channel image

__device__ __forceinline__ float lrelu(float x) { return x >= 0.f ? x : NEG * x; }

// -----------------------------------------------------------------------------
// K1: grid 768 = (img = b*NH*LK + n*LK + j) * 4 + cg, 256 threads (1/pixel).
// Each block handles an 8-channel slice (cg) of one head-image:
//  - project 8 V out-channels -> vh (global)
//  - project 8 K out-channels -> zero-padded LDS
//  - 5x5 conv partial over those 8 channels -> atomicAdd into ck
// 4x more blocks than round 1 => 3 blocks/CU, serial LDS chain 800 -> 200 reads.
// -----------------------------------------------------------------------------
__global__ __launch_bounds__(256) void k_proj_conv(
    const float* __restrict__ kin, const float* __restrict__ vin,
    const float* __restrict__ wk, const float* __restrict__ bk,
    const float* __restrict__ wv, const float* __restrict__ bv,
    const float* __restrict__ wat,
    float* __restrict__ vh, float* __restrict__ ck)
{
    const int bx  = blockIdx.x;
    const int img = bx >> 2;           // (b*NH + n)*LK + j
    const int cg  = bx & 3;            // channel group: 8 channels
    const int b   = img / (NH * LK);
    const int n   = (img / LK) % NH;
    const int j   = img % LK;
    const int hw  = threadIdx.x;
    const int h   = hw >> 4, w = hw & 15;

    __shared__ float skh[8][CHPAD];

    // zero padded LDS (15 writes/thread), barrier comes before interior writes
    for (int idx = hw; idx < 8 * CHPAD; idx += 256) ((float*)skh)[idx] = 0.f;

    const float* kb = kin + (size_t)((b * LK + j) * DF) * HW + hw;
    const float* vb = vin + (size_t)((b * LK + j) * DF) * HW + hw;

    float xr[DF];

    // ---- V projection: 8 out-channels of this group ----
    #pragma unroll
    for (int c = 0; c < DF; c++) xr[c] = vb[c * HW];
    #pragma unroll
    for (int d = 0; d < 8; d++) {
        const int o = n * DM + cg * 8 + d;
        const float* wr = wv + o * DF;
        float acc = bv[o];
        #pragma unroll
        for (int c = 0; c < DF; c++) acc += xr[c] * wr[c];
        vh[(size_t)img * (DM * HW) + (cg * 8 + d) * HW + hw] = lrelu(acc);
    }

    // ---- K projection into padded LDS ----
    #pragma unroll
    for (int c = 0; c < DF; c++) xr[c] = kb[c * HW];
    __syncthreads();   // zero-fill complete before interior writes
    #pragma unroll
    for (int d = 0; d < 8; d++) {
        const int o = n * DM + cg * 8 + d;
        const float* wr = wk + o * DF;
        float acc = bk[o];
        #pragma unroll
        for (int c = 0; c < DF; c++) acc += xr[c] * wr[c];
        skh[d][(h + 2) * PITCH + (w + 2)] = lrelu(acc);
    }
    __syncthreads();

    // ---- 5x5 conv partial over 8 channels (padding baked into LDS) ----
    float acc = 0.f;
    #pragma unroll
    for (int lc = 0; lc < 8; lc++) {
        const float* wc = wat + (cg * 8 + lc) * 25;
        #pragma unroll
        for (int ky = 0; ky < 5; ky++) {
            const float* row = &skh[lc][(h + ky) * PITCH + w];
            #pragma unroll
            for (int kx = 0; kx < 5; kx++)
                acc += row[kx] * wc[ky * 5 + kx];
        }
    }
    atomicAdd(&ck[img * HW + hw], acc);   // ck zeroed via hipMemsetAsync
}

// -----------------------------------------------------------------------------
// K2: grid 256 = (bn = b*NH+n) * 32 + u, 256 threads.
//  - softmax over j (24) per pixel, in registers (b_attn/q-side cancel)
//  - u < 24: write attn slice for query i=u (identical for all i)
//  - all u:  res channel c=u = sum_j A[j] * vh[j,c]
// -----------------------------------------------------------------------------
__global__ __launch_bounds__(256) void k_softmax_res(
    const float* __restrict__ ck, const float* __restrict__ vh,
    float* __restrict__ res, float* __restrict__ attn_out)
{
    const int bn = blockIdx.x >> 5;   // 0..7
    const int u  = blockIdx.x & 31;   // 0..31
    const int hw = threadIdx.x;

    float e[LK];
    const float* cb = ck + bn * LK * HW + hw;
    float m = -1e30f;
    #pragma unroll
    for (int jj = 0; jj < LK; jj++) { e[jj] = cb[jj * HW]; m = fmaxf(m, e[jj]); }
    float s = 0.f;
    #pragma unroll
    for (int jj = 0; jj < LK; jj++) { e[jj] = __expf(e[jj] - m); s += e[jj]; }
    const float inv = 1.f / s;
    #pragma unroll
    for (int jj = 0; jj < LK; jj++) e[jj] *= inv;

    // attn output for query i=u (softmax over keys kills the q_i + b_attn terms)
    if (u < LQ) {
        float* ao = attn_out + (size_t)((bn * LQ + u) * LK) * HW + hw;
        #pragma unroll
        for (int jj = 0; jj < LK; jj++) ao[jj * HW] = e[jj];
    }

    // res channel c = u
    const float* vp = vh + (size_t)(bn * LK) * (DM * HW) + u * HW + hw;
    float acc = 0.f;
    #pragma unroll
    for (int jj = 0; jj < LK; jj++) acc += e[jj] * vp[(size_t)jj * DM * HW];
    res[(bn * DM + u) * HW + hw] = acc;
}

// -----------------------------------------------------------------------------
// K3: final FC (128 -> 32), broadcast over l. grid 256 = b*128 + o*4 + lg,
// each block stores 6 of the 24 identical l-slices.
// -----------------------------------------------------------------------------
__global__ __launch_bounds__(256) void k_fc(
    const float* __restrict__ res, const float* __restrict__ wfc,
    float* __restrict__ out)
{
    const int bx = blockIdx.x;
    const int b  = bx >> 7;
    const int o  = (bx >> 2) & 31;
    const int lg = bx & 3;
    const int hw = threadIdx.x;

    const float* rp = res + (size_t)b * (NH * DM) * HW + hw;
    const float* wr = wfc + o * (NH * DM);
    float acc = 0.f;
    #pragma unroll
    for (int nc = 0; nc < NH * DM; nc++) acc += wr[nc] * rp[nc * HW];

    #pragma unroll
    for (int l = lg * 6; l < lg * 6 + 6; l++)
        out[(size_t)((b * LQ + l) * DM + o) * HW + hw] = acc;
}

// -----------------------------------------------------------------------------
extern "C" void kernel_launch(void* const* d_in, const int* in_sizes, int n_in,
                              void* d_out, int out_size, void* d_ws, size_t ws_size,
                              hipStream_t stream)
{
    // setup_inputs order: q,k,v,wq,bq,wk,bk,wv,bv,w_attn,b_attn,w_fc
    const float* k_in = (const float*)d_in[1];
    const float* v_in = (const float*)d_in[2];
    const float* wk   = (const float*)d_in[5];
    const float* bk   = (const float*)d_in[6];
    const float* wv   = (const float*)d_in[7];
    const float* bv   = (const float*)d_in[8];
    const float* wat  = (const float*)d_in[9];
    const float* wfc  = (const float*)d_in[11];
    // q, wq, bq, b_attn are provably unused (cancel in softmax over keys).

    float* out  = (float*)d_out;                       // (B,LQ,DM,H,W) = 393216
    float* attn = out + (size_t)BB * LQ * DM * HW;     // (B,NH,LQ,LK,1,H,W)

    float* vh  = (float*)d_ws;                                  // 1,572,864 f
    float* ck  = vh + (size_t)BB * NH * LK * DM * HW;           //    49,152 f
    float* res = ck + (size_t)BB * NH * LK * HW;                //    65,536 f
    // total ws use: 6.75 MB — identical to round 1 (known to fit)

    hipMemsetAsync(ck, 0, (size_t)BB * NH * LK * HW * sizeof(float), stream);
    hipLaunchKernelGGL(k_proj_conv, dim3(BB * NH * LK * 4), dim3(256), 0, stream,
                       k_in, v_in, wk, bk, wv, bv, wat, vh, ck);
    hipLaunchKernelGGL(k_softmax_res, dim3(BB * NH * 32), dim3(256), 0, stream,
                       ck, vh, res, attn);
    hipLaunchKernelGGL(k_fc, dim3(BB * DM * 4), dim3(256), 0, stream,
                       res, wfc, out);
}

// Round 3
// 101.215 us; speedup vs baseline: 1.3273x; 1.0119x over previous
//
#include <hip/hip_runtime.h>
#include <math.h>

// Problem constants (from reference)
#define BB   2
#define LQ   24
#define LK   24
#define NH   4
#define DM   32     // d_model
#define DF   32     // d_feat
#define HW   256    // 16x16
#define NEG  0.1f

// Padded LDS image: 20 rows, pitch 24 floats -> 2-way bank aliasing (free).
#define PITCH 24
#define CHPAD (20 * PITCH)   // 480 floats per channel image

#define NIMG (BB * NH * LK)  // 192 head-images

__device__ __forceinline__ float lrelu(float x) { return x >= 0.f ? x : NEG * x; }

// -----------------------------------------------------------------------------
// K1: grid 768 = img * 4 + cg, 256 threads (1 thread/pixel).
// Each block: 8-channel slice of one head-image.
//  - project 8 V out-channels -> vh (global)
//  - project 8 K out-channels -> zero-padded LDS
//  - 5x5 conv partial over those 8 channels -> PLAIN store to ck4[cg]
// (round 2 used atomicAdd + a memset node; partial buffers remove both)
// -----------------------------------------------------------------------------
__global__ __launch_bounds__(256) void k_proj_conv(
    const float* __restrict__ kin, const float* __restrict__ vin,
    const float* __restrict__ wk, const float* __restrict__ bk,
    const float* __restrict__ wv, const float* __restrict__ bv,
    const float* __restrict__ wat,
    float* __restrict__ vh, float* __restrict__ ck4)
{
    const int bx  = blockIdx.x;
    const int img = bx >> 2;           // (b*NH + n)*LK + j
    const int cg  = bx & 3;            // channel group: 8 channels
    const int b   = img / (NH * LK);
    const int n   = (img / LK) % NH;
    const int j   = img % LK;
    const int hw  = threadIdx.x;
    const int h   = hw >> 4, w = hw & 15;

    __shared__ float skh[8][CHPAD];

    for (int idx = hw; idx < 8 * CHPAD; idx += 256) ((float*)skh)[idx] = 0.f;

    const float* kb = kin + (size_t)((b * LK + j) * DF) * HW + hw;
    const float* vb = vin + (size_t)((b * LK + j) * DF) * HW + hw;

    float xr[DF];

    // ---- V projection: 8 out-channels of this group ----
    #pragma unroll
    for (int c = 0; c < DF; c++) xr[c] = vb[c * HW];
    #pragma unroll
    for (int d = 0; d < 8; d++) {
        const int o = n * DM + cg * 8 + d;
        const float* wr = wv + o * DF;
        float acc = bv[o];
        #pragma unroll
        for (int c = 0; c < DF; c++) acc += xr[c] * wr[c];
        vh[(size_t)img * (DM * HW) + (cg * 8 + d) * HW + hw] = lrelu(acc);
    }

    // ---- K projection into padded LDS ----
    #pragma unroll
    for (int c = 0; c < DF; c++) xr[c] = kb[c * HW];
    __syncthreads();   // zero-fill complete before interior writes
    #pragma unroll
    for (int d = 0; d < 8; d++) {
        const int o = n * DM + cg * 8 + d;
        const float* wr = wk + o * DF;
        float acc = bk[o];
        #pragma unroll
        for (int c = 0; c < DF; c++) acc += xr[c] * wr[c];
        skh[d][(h + 2) * PITCH + (w + 2)] = lrelu(acc);
    }
    __syncthreads();

    // ---- 5x5 conv partial over 8 channels (padding baked into LDS) ----
    float acc = 0.f;
    #pragma unroll
    for (int lc = 0; lc < 8; lc++) {
        const float* wc = wat + (cg * 8 + lc) * 25;
        #pragma unroll
        for (int ky = 0; ky < 5; ky++) {
            const float* row = &skh[lc][(h + ky) * PITCH + w];
            #pragma unroll
            for (int kx = 0; kx < 5; kx++)
                acc += row[kx] * wc[ky * 5 + kx];
        }
    }
    ck4[(size_t)(cg * NIMG + img) * HW + hw] = acc;
}

// -----------------------------------------------------------------------------
// K2: grid 448 = (bn = b*NH+n) * 56 + u, 256 threads (1 thread/pixel).
//  - per-pixel softmax over j (24) from the 4 conv partials, in registers
//    (q-side conv + b_attn cancel in the softmax over keys)
//  - u <  24: write attn slice for query i=u (identical for all i)
//  - u >= 24: res channel c=u-24 = sum_j A[j] * vh[j,c]
// Round 2 packed both jobs into 256 blocks (1 blk/CU, imbalanced); 448 gives
// 1.75 blk/CU and one job per block. Redundant softmax is ~100 cyc.
// -----------------------------------------------------------------------------
__global__ __launch_bounds__(256) void k_softmax_res(
    const float* __restrict__ ck4, const float* __restrict__ vh,
    float* __restrict__ res, float* __restrict__ attn_out)
{
    const int bn = blockIdx.x / 56;   // 0..7
    const int u  = blockIdx.x % 56;   // 0..55
    const int hw = threadIdx.x;

    float e[LK];
    const float* c0 = ck4 + (size_t)(0 * NIMG + bn * LK) * HW + hw;
    const float* c1 = ck4 + (size_t)(1 * NIMG + bn * LK) * HW + hw;
    const float* c2 = ck4 + (size_t)(2 * NIMG + bn * LK) * HW + hw;
    const float* c3 = ck4 + (size_t)(3 * NIMG + bn * LK) * HW + hw;
    float m = -1e30f;
    #pragma unroll
    for (int jj = 0; jj < LK; jj++) {
        e[jj] = (c0[jj * HW] + c1[jj * HW]) + (c2[jj * HW] + c3[jj * HW]);
        m = fmaxf(m, e[jj]);
    }
    float s = 0.f;
    #pragma unroll
    for (int jj = 0; jj < LK; jj++) { e[jj] = __expf(e[jj] - m); s += e[jj]; }
    const float inv = 1.f / s;
    #pragma unroll
    for (int jj = 0; jj < LK; jj++) e[jj] *= inv;

    if (u < LQ) {
        // attn output for query i=u (same for every i)
        float* ao = attn_out + (size_t)((bn * LQ + u) * LK) * HW + hw;
        #pragma unroll
        for (int jj = 0; jj < LK; jj++) ao[jj * HW] = e[jj];
    } else {
        // res channel c = u - 24
        const int c = u - LQ;
        const float* vp = vh + (size_t)(bn * LK) * (DM * HW) + c * HW + hw;
        float acc = 0.f;
        #pragma unroll
        for (int jj = 0; jj < LK; jj++) acc += e[jj] * vp[(size_t)jj * DM * HW];
        res[(bn * DM + c) * HW + hw] = acc;
    }
}

// -----------------------------------------------------------------------------
// K3: final FC (128 -> 32), broadcast over l. grid 256 = b*128 + o*4 + lg,
// each block stores 6 of the 24 identical l-slices.
// -----------------------------------------------------------------------------
__global__ __launch_bounds__(256) void k_fc(
    const float* __restrict__ res, const float* __restrict__ wfc,
    float* __restrict__ out)
{
    const int bx = blockIdx.x;
    const int b  = bx >> 7;
    const int o  = (bx >> 2) & 31;
    const int lg = bx & 3;
    const int hw = threadIdx.x;

    const float* rp = res + (size_t)b * (NH * DM) * HW + hw;
    const float* wr = wfc + o * (NH * DM);
    float acc = 0.f;
    #pragma unroll
    for (int nc = 0; nc < NH * DM; nc++) acc += wr[nc] * rp[nc * HW];

    #pragma unroll
    for (int l = lg * 6; l < lg * 6 + 6; l++)
        out[(size_t)((b * LQ + l) * DM + o) * HW + hw] = acc;
}

// -----------------------------------------------------------------------------
extern "C" void kernel_launch(void* const* d_in, const int* in_sizes, int n_in,
                              void* d_out, int out_size, void* d_ws, size_t ws_size,
                              hipStream_t stream)
{
    // setup_inputs order: q,k,v,wq,bq,wk,bk,wv,bv,w_attn,b_attn,w_fc
    const float* k_in = (const float*)d_in[1];
    const float* v_in = (const float*)d_in[2];
    const float* wk   = (const float*)d_in[5];
    const float* bk   = (const float*)d_in[6];
    const float* wv   = (const float*)d_in[7];
    const float* bv   = (const float*)d_in[8];
    const float* wat  = (const float*)d_in[9];
    const float* wfc  = (const float*)d_in[11];
    // q, wq, bq, b_attn are provably unused (cancel in softmax over keys).

    float* out  = (float*)d_out;                       // (B,LQ,DM,H,W)
    float* attn = out + (size_t)BB * LQ * DM * HW;     // (B,NH,LQ,LK,1,H,W)

    float* vh  = (float*)d_ws;                                   // 1,572,864 f
    float* ck4 = vh  + (size_t)BB * NH * LK * DM * HW;           //   196,608 f
    float* res = ck4 + (size_t)4 * NIMG * HW;                    //    65,536 f
    // total ws use: ~7.3 MB

    hipLaunchKernelGGL(k_proj_conv, dim3(NIMG * 4), dim3(256), 0, stream,
                       k_in, v_in, wk, bk, wv, bv, wat, vh, ck4);
    hipLaunchKernelGGL(k_softmax_res, dim3(BB * NH * 56), dim3(256), 0, stream,
                       ck4, vh, res, attn);
    hipLaunchKernelGGL(k_fc, dim3(BB * DM * 4), dim3(256), 0, stream,
                       res, wfc, out);
}